// Round 1
// baseline (352.348 us; speedup 1.0000x reference)
//
#include <hip/hip_runtime.h>

#define CC 128
#define HH 128
#define WW 128
#define NKD 21
#define RAD 10
#define WP 148          // 128 + 2*10 padded row
#define CHUNK 8         // channels per LDS chunk

__global__ __launch_bounds__(256, 2)
void corr_kernel(const float* __restrict__ in, float* __restrict__ out) {
    // ---- block -> (b, h-octet, dy) with XCD-aware swizzle ----
    // n%8 = XCD; each XCD owns 8 (b,h8) groups x 21 dy, dy fastest -> the 21
    // blocks sharing a (b,h8) run close together on one XCD (target-row L2 reuse).
    int n  = blockIdx.x;
    int x  = n & 7;
    int r  = n >> 3;            // 0..167
    int g  = r / 21;            // 0..7
    int dy = r - g * 21;        // 0..20
    int gl = x * 8 + g;         // 0..63
    int b  = gl >> 4;
    int h0 = (gl & 15) << 3;    // h-octet base

    const float* src = in + (size_t)(b * 2 + 0) * CC * HH * WW;
    const float* tgt = in + (size_t)(b * 2 + 1) * CC * HH * WW;

    __shared__ float s_src[CHUNK][8][WW];   // 32 KB
    __shared__ float s_tgt[CHUNK][8][WP];   // 37 KB

    const int tid = threadIdx.x;
    const int wq  = tid & 31;       // w-quad id
    const int hl  = tid >> 5;       // 0..7 local h row
    const int w0  = wq << 2;

    float acc[NKD][4];
#pragma unroll
    for (int i = 0; i < NKD; ++i)
#pragma unroll
        for (int j = 0; j < 4; ++j) acc[i][j] = 0.f;

    for (int cc = 0; cc < CC; cc += CHUNK) {
        __syncthreads();   // previous chunk's compute done before restage

        // ---- stage src chunk: 8c x 8h x 128w = 2048 float4, 8 per thread ----
#pragma unroll
        for (int i = 0; i < 8; ++i) {
            int f   = tid + i * 256;
            int row = f >> 5;            // cl*8 + hr
            int w4  = (f & 31) << 2;
            int cl  = row >> 3, hr = row & 7;
            *(float4*)&s_src[cl][hr][w4] =
                *(const float4*)&src[(size_t)(cc + cl) * (HH * WW) + (h0 + hr) * WW + w4];
        }

        // ---- stage tgt chunk: 8c x 8h' x 148, zero-padded; float2 granular ----
        for (int f = tid; f < CHUNK * 8 * (WP / 2); f += 256) {
            int row = f / (WP / 2);
            int p2  = f - row * (WP / 2);
            int cl  = row >> 3, hr = row & 7;
            int hp  = h0 + hr + dy - RAD;
            int wg  = p2 * 2 - RAD;
            float2 v = make_float2(0.f, 0.f);
            if (hp >= 0 && hp < HH) {
                const float* trow = &tgt[(size_t)(cc + cl) * (HH * WW) + hp * WW];
                if (wg >= 0 && wg + 1 < WW) {
                    v = *(const float2*)&trow[wg];       // 8B-aligned (wg even)
                } else {
                    if (wg >= 0 && wg < WW)         v.x = trow[wg];
                    if (wg + 1 >= 0 && wg + 1 < WW) v.y = trow[wg + 1];
                }
            }
            *(float2*)&s_tgt[cl][hr][p2 * 2] = v;
        }
        __syncthreads();

        // ---- compute: per channel, 1+6 aligned b128 LDS reads feed 84 FMAs ----
#pragma unroll
        for (int cl = 0; cl < CHUNK; ++cl) {
            float4 s4 = *(float4*)&s_src[cl][hl][w0];
            float s[4] = {s4.x, s4.y, s4.z, s4.w};
            float win[24];
#pragma unroll
            for (int k = 0; k < 6; ++k) {
                float4 t4 = *(float4*)&s_tgt[cl][hl][w0 + k * 4];
                win[k * 4 + 0] = t4.x; win[k * 4 + 1] = t4.y;
                win[k * 4 + 2] = t4.z; win[k * 4 + 3] = t4.w;
            }
#pragma unroll
            for (int dx = 0; dx < NKD; ++dx)
#pragma unroll
                for (int j = 0; j < 4; ++j)
                    acc[dx][j] = fmaf(s[j], win[dx + j], acc[dx][j]);
        }
    }

    // ---- epilogue: mean over C, coalesced b128 stores ----
    const float scale = 1.f / 128.f;
#pragma unroll
    for (int dx = 0; dx < NKD; ++dx) {
        float4 o;
        o.x = acc[dx][0] * scale; o.y = acc[dx][1] * scale;
        o.z = acc[dx][2] * scale; o.w = acc[dx][3] * scale;
        size_t off = (((size_t)b * (NKD * NKD) + dy * NKD + dx) * HH + (h0 + hl)) * WW + w0;
        *(float4*)&out[off] = o;
    }
}

extern "C" void kernel_launch(void* const* d_in, const int* in_sizes, int n_in,
                              void* d_out, int out_size, void* d_ws, size_t ws_size,
                              hipStream_t stream) {
    const float* in = (const float*)d_in[0];
    float* out = (float*)d_out;
    dim3 grid(1344), block(256);
    hipLaunchKernelGGL(corr_kernel, grid, block, 0, stream, in, out);
}

// Round 3
// 186.401 us; speedup vs baseline: 1.8903x; 1.8903x over previous
//
#include <hip/hip_runtime.h>

#define CC 128
#define HH 128
#define WW 128
#define NKD 21
#define RAD 10
#define WP 148          // 128 + 2*10 padded row (in w positions)
#define CH2 4           // channel-PAIRS per chunk (8 channels)

typedef __fp16   h2   __attribute__((ext_vector_type(2)));   // storage (cvt_pkrtz type)
typedef _Float16 f16x2 __attribute__((ext_vector_type(2)));  // fdot2 operand type

__device__ __forceinline__ float dot2(h2 a, h2 b, float c) {
#if __has_builtin(__builtin_amdgcn_fdot2)
    return __builtin_amdgcn_fdot2(__builtin_bit_cast(f16x2, a),
                                  __builtin_bit_cast(f16x2, b), c, false);
#else
    return c + (float)a.x * (float)b.x + (float)a.y * (float)b.y;
#endif
}

union Q4 { float4 f; h2 h[4]; };
union Q2 { float2 f; h2 h[2]; };

__global__ __launch_bounds__(128, 4)
void corr_kernel(const float* __restrict__ in, float* __restrict__ out) {
    // ---- block -> (b, h-quad, dy); n%8 = XCD, dy fastest within an XCD ----
    int n  = blockIdx.x;
    int x  = n & 7;
    int r  = n >> 3;            // 0..335
    int g  = r / 21;            // 0..15
    int dy = r - g * 21;        // 0..20
    int gl = x * 16 + g;        // 0..127
    int b  = gl >> 5;           // 0..3
    int h0 = (gl & 31) << 2;    // h-quad base

    const float* src = in + (size_t)(b * 2 + 0) * CC * HH * WW;
    const float* tgt = in + (size_t)(b * 2 + 1) * CC * HH * WW;

    __shared__ h2 s_src[CH2][4][WW];   // 8 KB   (c-pair packed f16)
    __shared__ h2 s_tgt[CH2][4][WP];   // 9.25 KB

    const int tid = threadIdx.x;
    const int wq  = tid & 31;       // w-quad id
    const int hl  = tid >> 5;       // 0..3 local h row
    const int w0  = wq << 2;

    float acc[NKD][4];
#pragma unroll
    for (int i = 0; i < NKD; ++i)
#pragma unroll
        for (int j = 0; j < 4; ++j) acc[i][j] = 0.f;

    for (int cc = 0; cc < CC; cc += 2 * CH2) {
        __syncthreads();   // previous chunk's compute done before restage

        // ---- stage src chunk: 4cl2 x 4h x 128w half2 = 512 b128 items ----
#pragma unroll
        for (int i = 0; i < 4; ++i) {
            int f   = tid + i * 128;
            int w4  = (f & 31) << 2;
            int row = f >> 5;            // 0..15
            int cl2 = row >> 2, hr = row & 3;
            const float* p0 = src + (size_t)(cc + 2 * cl2) * (HH * WW) + (h0 + hr) * WW + w4;
            float4 a = *(const float4*)p0;
            float4 c = *(const float4*)(p0 + HH * WW);
            Q4 q;
            q.h[0] = __builtin_amdgcn_cvt_pkrtz(a.x, c.x);
            q.h[1] = __builtin_amdgcn_cvt_pkrtz(a.y, c.y);
            q.h[2] = __builtin_amdgcn_cvt_pkrtz(a.z, c.z);
            q.h[3] = __builtin_amdgcn_cvt_pkrtz(a.w, c.w);
            *(float4*)&s_src[cl2][hr][w4] = q.f;
        }

        // ---- stage tgt chunk: 4cl2 x 4h' x 74 (2w x 2c) items, padded ----
        for (int f = tid; f < CH2 * 4 * (WP / 2); f += 128) {
            int row = f / (WP / 2);          // 0..15
            int p2  = f - row * (WP / 2);    // 0..73
            int cl2 = row >> 2, hr = row & 3;
            int hp  = h0 + hr + dy - RAD;
            int wg  = p2 * 2 - RAD;
            float2 v0 = make_float2(0.f, 0.f), v1 = v0;
            if (hp >= 0 && hp < HH) {
                const float* r0 = tgt + (size_t)(cc + 2 * cl2) * (HH * WW) + hp * WW;
                const float* r1 = r0 + HH * WW;
                if (wg >= 0 && wg + 1 < WW) {
                    v0 = *(const float2*)(r0 + wg);   // wg even -> 8B aligned
                    v1 = *(const float2*)(r1 + wg);
                } else {
                    if (wg >= 0 && wg < WW)           { v0.x = r0[wg];     v1.x = r1[wg];     }
                    if (wg + 1 >= 0 && wg + 1 < WW)   { v0.y = r0[wg + 1]; v1.y = r1[wg + 1]; }
                }
            }
            Q2 u;
            u.h[0] = __builtin_amdgcn_cvt_pkrtz(v0.x, v1.x);
            u.h[1] = __builtin_amdgcn_cvt_pkrtz(v0.y, v1.y);
            *(float2*)&s_tgt[cl2][hr][p2 * 2] = u.f;
        }
        __syncthreads();

        // ---- compute: per c-pair, 1+6 b128 LDS reads feed 84 dot2 ----
#pragma unroll
        for (int cl2 = 0; cl2 < CH2; ++cl2) {
            Q4 sq; sq.f = *(float4*)&s_src[cl2][hl][w0];
            h2 win[24];
#pragma unroll
            for (int k = 0; k < 6; ++k) {
                Q4 t; t.f = *(float4*)&s_tgt[cl2][hl][w0 + k * 4];
                win[k * 4 + 0] = t.h[0]; win[k * 4 + 1] = t.h[1];
                win[k * 4 + 2] = t.h[2]; win[k * 4 + 3] = t.h[3];
            }
#pragma unroll
            for (int dx = 0; dx < NKD; ++dx)
#pragma unroll
                for (int j = 0; j < 4; ++j)
                    acc[dx][j] = dot2(sq.h[j], win[dx + j], acc[dx][j]);
        }
    }

    // ---- epilogue: mean over C, coalesced b128 stores ----
    const float scale = 1.f / 128.f;
#pragma unroll
    for (int dx = 0; dx < NKD; ++dx) {
        float4 o;
        o.x = acc[dx][0] * scale; o.y = acc[dx][1] * scale;
        o.z = acc[dx][2] * scale; o.w = acc[dx][3] * scale;
        size_t off = (((size_t)b * (NKD * NKD) + dy * NKD + dx) * HH + (h0 + hl)) * WW + w0;
        *(float4*)&out[off] = o;
    }
}

extern "C" void kernel_launch(void* const* d_in, const int* in_sizes, int n_in,
                              void* d_out, int out_size, void* d_ws, size_t ws_size,
                              hipStream_t stream) {
    const float* in = (const float*)d_in[0];
    float* out = (float*)d_out;
    dim3 grid(2688), block(128);
    hipLaunchKernelGGL(corr_kernel, grid, block, 0, stream, in, out);
}

// Round 4
// 78.391 us; speedup vs baseline: 4.4948x; 2.3778x over previous
//
#include <hip/hip_runtime.h>

#define HH 128
#define WW 128
#define CCH 128
#define NKD 21
#define RAD 10
#define PTOT 160          // padded p rows in tgt image (p = w + dx, 0..147, padded to 160)
#define HPAD 148          // tgt image h rows (hp = h+dy index 0..147)

typedef _Float16 f16x8 __attribute__((ext_vector_type(8)));
typedef float    f32x4 __attribute__((ext_vector_type(4)));
typedef __fp16   h2f   __attribute__((ext_vector_type(2)));

union PK { uint4 u; h2f h[4]; };

#define SRC_IMG_HALVES 16384          // 128w x 128c per (b,h) = 32KB
#define TGT_IMG_HALVES 20480          // 2ch x 160p x 64c per (b,hp) = 40KB

// ---------------- kernel 1a: pack src -> f16 [w][c] swizzled image ----------------
__global__ __launch_bounds__(256)
void pack_src(const float* __restrict__ in, __fp16* __restrict__ img) {
    int n = blockIdx.x;                 // 512: b*128 + h
    int b = n >> 7, h = n & 127;
    const float* src = in + (size_t)(b * 2 + 0) * CCH * HH * WW + (size_t)h * WW;
    __shared__ __align__(16) __fp16 s[128 * 128];   // [w][c-slot swizzled] 32KB
    int tid = threadIdx.x;
    int w = tid & 127, half = tid >> 7;
#pragma unroll
    for (int t8 = 0; t8 < 8; ++t8) {
        int t = half * 8 + t8;          // c-block 0..15
        float v[8];
#pragma unroll
        for (int j = 0; j < 8; ++j) v[j] = src[(size_t)(t * 8 + j) * (HH * WW) + w];
        PK q;
        q.h[0] = __builtin_amdgcn_cvt_pkrtz(v[0], v[1]);
        q.h[1] = __builtin_amdgcn_cvt_pkrtz(v[2], v[3]);
        q.h[2] = __builtin_amdgcn_cvt_pkrtz(v[4], v[5]);
        q.h[3] = __builtin_amdgcn_cvt_pkrtz(v[6], v[7]);
        int slot = t ^ (w & 7);
        *(uint4*)&s[w * 128 + slot * 8] = q.u;
    }
    __syncthreads();
    uint4* gi = (uint4*)(img + (size_t)n * SRC_IMG_HALVES);
    const uint4* si = (const uint4*)s;
#pragma unroll
    for (int k = 0; k < 8; ++k) gi[k * 256 + tid] = si[k * 256 + tid];
}

// ------------- kernel 1b: pack tgt -> f16 [ch][p][c64] swizzled, zero-padded -------------
__global__ __launch_bounds__(256)
void pack_tgt(const float* __restrict__ in, __fp16* __restrict__ img) {
    int n = blockIdx.x;                 // 592: b*148 + i, i = hp index (row = i-10)
    int b = n / HPAD, i = n - b * HPAD;
    int tid = threadIdx.x;
    uint4* gi = (uint4*)(img + (size_t)n * TGT_IMG_HALVES);
    if (i < RAD || i > 137) {           // h out of range -> all-zero image
        uint4 z = make_uint4(0, 0, 0, 0);
#pragma unroll
        for (int k = 0; k < 10; ++k) gi[k * 256 + tid] = z;
        return;
    }
    const float* tg = in + (size_t)(b * 2 + 1) * CCH * HH * WW + (size_t)(i - RAD) * WW;
    __shared__ __align__(16) __fp16 s[2 * PTOT * 64];   // 40KB
    {   // zero-fill all (covers p<10, p>=138 pad rows)
        uint4 z = make_uint4(0, 0, 0, 0);
        uint4* sp = (uint4*)s;
#pragma unroll
        for (int k = 0; k < 10; ++k) sp[k * 256 + tid] = z;
    }
    __syncthreads();
    int w = tid & 127, ch = tid >> 7;
    int p = w + RAD;
#pragma unroll
    for (int t8 = 0; t8 < 8; ++t8) {
        float v[8];
#pragma unroll
        for (int j = 0; j < 8; ++j)
            v[j] = tg[(size_t)(ch * 64 + t8 * 8 + j) * (HH * WW) + w];
        PK q;
        q.h[0] = __builtin_amdgcn_cvt_pkrtz(v[0], v[1]);
        q.h[1] = __builtin_amdgcn_cvt_pkrtz(v[2], v[3]);
        q.h[2] = __builtin_amdgcn_cvt_pkrtz(v[4], v[5]);
        q.h[3] = __builtin_amdgcn_cvt_pkrtz(v[6], v[7]);
        int slot = t8 ^ (p & 7);
        *(uint4*)&s[(ch * PTOT + p) * 64 + slot * 8] = q.u;
    }
    __syncthreads();
    const uint4* si = (const uint4*)s;
#pragma unroll
    for (int k = 0; k < 10; ++k) gi[k * 256 + tid] = si[k * 256 + tid];
}

// ---------------- kernel 2: banded MFMA correlation ----------------
__global__ __launch_bounds__(256, 2)
void corr_mfma(const __fp16* __restrict__ img_src, const __fp16* __restrict__ img_tgt,
               float* __restrict__ out) {
    int n = blockIdx.x;                 // 512
    int xcd = n & 7, idx = n >> 3;
    int gl = xcd * 64 + idx;            // h-contiguous per XCD
    int b = gl >> 7, h = gl & 127;

    __shared__ __align__(16) __fp16 s_src[128 * 128];   // 32KB
    __shared__ __align__(16) __fp16 s_tgt[PTOT * 64];   // 20KB (one 64c chunk)
    __shared__ float s_o[128 * 48];                     // 24KB epilogue bounce

    int tid = threadIdx.x;
    int q = tid >> 6, lane = tid & 63, r = lane & 15, g = lane >> 4;

    {   // stage src image (linear copy; swizzle baked in)
        const uint4* gs = (const uint4*)(img_src + (size_t)gl * SRC_IMG_HALVES);
        uint4* sp = (uint4*)s_src;
#pragma unroll
        for (int k = 0; k < 8; ++k) sp[k * 256 + tid] = gs[k * 256 + tid];
    }
    __syncthreads();

    // A-fragments in registers for the whole kernel: wave q owns w-tiles 2q, 2q+1
    f16x8 a[2][4];
#pragma unroll
    for (int wi = 0; wi < 2; ++wi) {
        int wrow = (2 * q + wi) * 16 + r;
#pragma unroll
        for (int ks = 0; ks < 4; ++ks) {
            int slot = (ks * 4 + g) ^ (wrow & 7);
            a[wi][ks] = *(const f16x8*)&s_src[wrow * 128 + slot * 8];
        }
    }

    const __fp16* tgb = img_tgt + (size_t)(b * HPAD) * TGT_IMG_HALVES;
    float* outb = out + (size_t)b * (NKD * NKD) * (HH * WW) + (size_t)h * WW;

    for (int dy = 0; dy < NKD; ++dy) {
        f32x4 acc[2][3];
#pragma unroll
        for (int wi = 0; wi < 2; ++wi)
#pragma unroll
            for (int pj = 0; pj < 3; ++pj)
#pragma unroll
                for (int j = 0; j < 4; ++j) acc[wi][pj][j] = 0.f;

        const uint4* gt = (const uint4*)(tgb + (size_t)(h + dy) * TGT_IMG_HALVES);

#pragma unroll
        for (int ch = 0; ch < 2; ++ch) {
            {   // stage tgt chunk (1280 uint4)
                uint4* sp = (uint4*)s_tgt;
#pragma unroll
                for (int k = 0; k < 5; ++k)
                    sp[k * 256 + tid] = gt[ch * 1280 + k * 256 + tid];
            }
            __syncthreads();
#pragma unroll
            for (int ks2 = 0; ks2 < 2; ++ks2) {
                f16x8 bfr[4];
#pragma unroll
                for (int pi = 0; pi < 4; ++pi) {
                    int prow = (2 * q + pi) * 16 + r;
                    int slot = (ks2 * 4 + g) ^ (prow & 7);
                    bfr[pi] = *(const f16x8*)&s_tgt[prow * 64 + slot * 8];
                }
#pragma unroll
                for (int wi = 0; wi < 2; ++wi)
#pragma unroll
                    for (int pj = 0; pj < 3; ++pj)
                        acc[wi][pj] = __builtin_amdgcn_mfma_f32_16x16x32_f16(
                            a[wi][ch * 2 + ks2], bfr[wi + pj], acc[wi][pj], 0, 0, 0);
            }
            __syncthreads();   // all waves done reading s_tgt before restage / epilogue reuse
        }

        // ---- epilogue: acc -> s_o (disjoint rows per wave), then coalesced stores ----
#pragma unroll
        for (int wi = 0; wi < 2; ++wi) {
            int wbase = (2 * q + wi) * 16 + 4 * g;
#pragma unroll
            for (int pj = 0; pj < 3; ++pj)
#pragma unroll
                for (int j = 0; j < 4; ++j)
                    s_o[(wbase + j) * 48 + pj * 16 + r] = acc[wi][pj][j];
        }
        __syncthreads();

        const float sc = 1.f / 128.f;
        for (int f = tid; f < NKD * 32; f += 256) {
            int dx = f >> 5, w4 = (f & 31) * 4;
            float4 v;
            v.x = s_o[(w4 + 0) * 48 + ((w4 + 0) & 15) + dx] * sc;
            v.y = s_o[(w4 + 1) * 48 + ((w4 + 1) & 15) + dx] * sc;
            v.z = s_o[(w4 + 2) * 48 + ((w4 + 2) & 15) + dx] * sc;
            v.w = s_o[(w4 + 3) * 48 + ((w4 + 3) & 15) + dx] * sc;
            *(float4*)&outb[(size_t)(dy * NKD + dx) * (HH * WW) + w4] = v;
        }
        __syncthreads();
    }
}

extern "C" void kernel_launch(void* const* d_in, const int* in_sizes, int n_in,
                              void* d_out, int out_size, void* d_ws, size_t ws_size,
                              hipStream_t stream) {
    const float* in = (const float*)d_in[0];
    float* out = (float*)d_out;
    __fp16* img_src = (__fp16*)d_ws;
    __fp16* img_tgt = (__fp16*)((char*)d_ws + (size_t)512 * SRC_IMG_HALVES * 2);

    hipLaunchKernelGGL(pack_src, dim3(512), dim3(256), 0, stream, in, img_src);
    hipLaunchKernelGGL(pack_tgt, dim3(4 * HPAD), dim3(256), 0, stream, in, img_tgt);
    hipLaunchKernelGGL(corr_mfma, dim3(512), dim3(256), 0, stream, img_src, img_tgt, out);
}

// Round 5
// 64.132 us; speedup vs baseline: 5.4941x; 1.2223x over previous
//
#include <hip/hip_runtime.h>

#define HH 128
#define WW 128
#define CCH 128
#define NKD 21
#define RAD 10
#define PTOT 160          // padded p rows in tgt image (p = w + dx, 0..147, padded)
#define HPAD 148          // tgt image count per b (hp = h+dy, 0..147)
#define TGT_IMG_HALVES (2 * PTOT * 64)   // 20480 halves = 40KB per (b,hp)

typedef _Float16 f16x8 __attribute__((ext_vector_type(8)));
typedef float    f32x4 __attribute__((ext_vector_type(4)));
typedef __fp16   h2f   __attribute__((ext_vector_type(2)));

union PK { uint4 u; h2f h[4]; };

// ------------- kernel 1: pack tgt -> f16 [ch][p][c64] swizzled, zero-padded -------------
__global__ __launch_bounds__(256)
void pack_tgt(const float* __restrict__ in, __fp16* __restrict__ img) {
    int n = blockIdx.x;                 // 592: b*148 + i, i = hp index (tgt row = i-10)
    int b = n / HPAD, i = n - b * HPAD;
    int tid = threadIdx.x;
    uint4* gi = (uint4*)(img + (size_t)n * TGT_IMG_HALVES);
    if (i < RAD || i > 137) {           // h out of range -> all-zero image
        uint4 z = make_uint4(0, 0, 0, 0);
#pragma unroll
        for (int k = 0; k < 10; ++k) gi[k * 256 + tid] = z;
        return;
    }
    const float* tg = in + (size_t)(b * 2 + 1) * CCH * HH * WW + (size_t)(i - RAD) * WW;
    __shared__ __align__(16) __fp16 s[2 * PTOT * 64];   // 40KB
    {   // zero-fill (covers p<10, p>=138 pad rows)
        uint4 z = make_uint4(0, 0, 0, 0);
        uint4* sp = (uint4*)s;
#pragma unroll
        for (int k = 0; k < 10; ++k) sp[k * 256 + tid] = z;
    }
    __syncthreads();
    int w = tid & 127, ch = tid >> 7;
    int p = w + RAD;
#pragma unroll
    for (int t8 = 0; t8 < 8; ++t8) {
        float v[8];
#pragma unroll
        for (int j = 0; j < 8; ++j)
            v[j] = tg[(size_t)(ch * 64 + t8 * 8 + j) * (HH * WW) + w];
        PK q;
        q.h[0] = __builtin_amdgcn_cvt_pkrtz(v[0], v[1]);
        q.h[1] = __builtin_amdgcn_cvt_pkrtz(v[2], v[3]);
        q.h[2] = __builtin_amdgcn_cvt_pkrtz(v[4], v[5]);
        q.h[3] = __builtin_amdgcn_cvt_pkrtz(v[6], v[7]);
        int slot = t8 ^ (p & 7);
        *(uint4*)&s[(ch * PTOT + p) * 64 + slot * 8] = q.u;
    }
    __syncthreads();
    const uint4* si = (const uint4*)s;
#pragma unroll
    for (int k = 0; k < 10; ++k) gi[k * 256 + tid] = si[k * 256 + tid];
}

// ---------------- kernel 2: fused src-pack + banded MFMA correlation ----------------
__global__ __launch_bounds__(256, 2)
void corr_mfma(const float* __restrict__ in, const __fp16* __restrict__ img_tgt,
               float* __restrict__ out) {
    int n = blockIdx.x;                 // 512
    int xcd = n & 7, idx = n >> 3;
    int gl = xcd * 64 + idx;            // h-contiguous per XCD
    int b = gl >> 7, h = gl & 127;

    __shared__ __align__(16) __fp16 s_src[128 * 128];   // 32KB
    __shared__ __align__(16) __fp16 s_tgt[PTOT * 64];   // 20KB (one 64c chunk)
    __shared__ float s_o[4][32 * 49];                   // 24.5KB, per-wave, padded rows

    int tid = threadIdx.x;
    int q = tid >> 6, lane = tid & 63, r = lane & 15, g = lane >> 4;

    // ---- pack src slice (b,h) in-kernel: fp32 [c][w] -> f16 [w][c] swizzled, x 1/128 ----
    {
        const float* src = in + (size_t)(b * 2) * CCH * HH * WW + (size_t)h * WW;
        const float sc = 1.f / 128.f;
        int w = tid & 127, half = tid >> 7;
#pragma unroll
        for (int t8 = 0; t8 < 8; ++t8) {
            int t = half * 8 + t8;          // c-block 0..15
            float v[8];
#pragma unroll
            for (int j = 0; j < 8; ++j) v[j] = src[(size_t)(t * 8 + j) * (HH * WW) + w] * sc;
            PK qq;
            qq.h[0] = __builtin_amdgcn_cvt_pkrtz(v[0], v[1]);
            qq.h[1] = __builtin_amdgcn_cvt_pkrtz(v[2], v[3]);
            qq.h[2] = __builtin_amdgcn_cvt_pkrtz(v[4], v[5]);
            qq.h[3] = __builtin_amdgcn_cvt_pkrtz(v[6], v[7]);
            int slot = t ^ (w & 7);
            *(uint4*)&s_src[w * 128 + slot * 8] = qq.u;
        }
    }
    __syncthreads();

    // ---- A-fragments in registers for the whole kernel: wave q owns w-tiles 2q,2q+1 ----
    f16x8 a[2][4];
#pragma unroll
    for (int wi = 0; wi < 2; ++wi) {
        int wrow = (2 * q + wi) * 16 + r;
#pragma unroll
        for (int ks = 0; ks < 4; ++ks) {
            int slot = (ks * 4 + g) ^ (wrow & 7);
            a[wi][ks] = *(const f16x8*)&s_src[wrow * 128 + slot * 8];
        }
    }

    const __fp16* tgb = img_tgt + (size_t)(b * HPAD) * TGT_IMG_HALVES;
    float* outb = out + (size_t)b * (NKD * NKD) * (HH * WW) + (size_t)h * WW;
    float* so = &s_o[q][0];

    for (int dy = 0; dy < NKD; ++dy) {
        f32x4 acc[2][3];
#pragma unroll
        for (int wi = 0; wi < 2; ++wi)
#pragma unroll
            for (int pj = 0; pj < 3; ++pj)
#pragma unroll
                for (int j = 0; j < 4; ++j) acc[wi][pj][j] = 0.f;

        const uint4* gt = (const uint4*)(tgb + (size_t)(h + dy) * TGT_IMG_HALVES);

#pragma unroll
        for (int ch = 0; ch < 2; ++ch) {
            // ---- DMA stage 20KB chunk: wave q copies 320 uint4 (5 x 64 lanes) ----
            {
                const uint4* gsrc = gt + ch * 1280 + q * 320 + lane;
                char* ldst = (char*)s_tgt + (size_t)(q * 320) * 16;
#pragma unroll
                for (int k = 0; k < 5; ++k)
                    __builtin_amdgcn_global_load_lds(
                        (const __attribute__((address_space(1))) void*)(gsrc + k * 64),
                        (__attribute__((address_space(3))) void*)(ldst + k * 1024),
                        16, 0, 0);
            }
            asm volatile("s_waitcnt vmcnt(0)" ::: "memory");
            __syncthreads();
#pragma unroll
            for (int ks2 = 0; ks2 < 2; ++ks2) {
                f16x8 bfr[4];
#pragma unroll
                for (int pi = 0; pi < 4; ++pi) {
                    int prow = (2 * q + pi) * 16 + r;
                    int slot = (ks2 * 4 + g) ^ (prow & 7);
                    bfr[pi] = *(const f16x8*)&s_tgt[prow * 64 + slot * 8];
                }
#pragma unroll
                for (int wi = 0; wi < 2; ++wi)
#pragma unroll
                    for (int pj = 0; pj < 3; ++pj)
                        acc[wi][pj] = __builtin_amdgcn_mfma_f32_16x16x32_f16(
                            a[wi][ch * 2 + ks2], bfr[wi + pj], acc[wi][pj], 0, 0, 0);
            }
            __syncthreads();   // all waves done reading s_tgt before restage
        }

        // ---- wave-local epilogue: acc -> private s_o slab, then coalesced stores ----
#pragma unroll
        for (int wi = 0; wi < 2; ++wi)
#pragma unroll
            for (int pj = 0; pj < 3; ++pj)
#pragma unroll
                for (int j = 0; j < 4; ++j)
                    so[(wi * 16 + 4 * g + j) * 49 + pj * 16 + r] = acc[wi][pj][j];
        asm volatile("s_waitcnt lgkmcnt(0)" ::: "memory");
        __builtin_amdgcn_sched_barrier(0);
#pragma unroll
        for (int k = 0; k < 3; ++k) {
            int f = k * 64 + lane;
            if (f < NKD * 8) {
                int dx = f >> 3, w4l = (f & 7) << 2;   // local w within wave's 32-w slab
                float4 v;
                v.x = so[(w4l + 0) * 49 + ((w4l + 0) & 15) + dx];
                v.y = so[(w4l + 1) * 49 + ((w4l + 1) & 15) + dx];
                v.z = so[(w4l + 2) * 49 + ((w4l + 2) & 15) + dx];
                v.w = so[(w4l + 3) * 49 + ((w4l + 3) & 15) + dx];
                *(float4*)&outb[(size_t)(dy * NKD + dx) * (HH * WW) + q * 32 + w4l] = v;
            }
        }
        // no barrier: s_o is wave-private; s_tgt reuse is guarded by the ch-loop barriers
    }
}

extern "C" void kernel_launch(void* const* d_in, const int* in_sizes, int n_in,
                              void* d_out, int out_size, void* d_ws, size_t ws_size,
                              hipStream_t stream) {
    const float* in = (const float*)d_in[0];
    float* out = (float*)d_out;
    __fp16* img_tgt = (__fp16*)d_ws;

    hipLaunchKernelGGL(pack_tgt, dim3(4 * HPAD), dim3(256), 0, stream, in, img_tgt);
    hipLaunchKernelGGL(corr_mfma, dim3(512), dim3(256), 0, stream, in, img_tgt, out);
}

// Round 6
// 61.811 us; speedup vs baseline: 5.7004x; 1.0376x over previous
//
#include <hip/hip_runtime.h>

#define HH 128
#define WW 128
#define CCH 128
#define NKD 21
#define RAD 10
#define PTOT 160          // padded p rows in tgt image (p = w + dx, 0..147, padded)
#define HPAD 148          // tgt images per b (hp = h+dy, 0..147)
#define TGT_IMG_HALVES (2 * PTOT * 64)   // 20480 halves = 40KB per (b,hp)

typedef _Float16 f16x8 __attribute__((ext_vector_type(8)));
typedef float    f32x4 __attribute__((ext_vector_type(4)));
typedef __fp16   h2f   __attribute__((ext_vector_type(2)));

union PK { uint4 u; h2f h[4]; };

// ------------- kernel 1: pack tgt -> f16 [ch][p][c64] swizzled, zero-padded -------------
__global__ __launch_bounds__(256)
void pack_tgt(const float* __restrict__ in, __fp16* __restrict__ img) {
    int n = blockIdx.x;                 // 592: b*148 + i, i = hp index (tgt row = i-10)
    int b = n / HPAD, i = n - b * HPAD;
    int tid = threadIdx.x;
    uint4* gi = (uint4*)(img + (size_t)n * TGT_IMG_HALVES);
    if (i < RAD || i > 137) {           // h out of range -> all-zero image
        uint4 z = make_uint4(0, 0, 0, 0);
#pragma unroll
        for (int k = 0; k < 10; ++k) gi[k * 256 + tid] = z;
        return;
    }
    const float* tg = in + (size_t)(b * 2 + 1) * CCH * HH * WW + (size_t)(i - RAD) * WW;
    __shared__ __align__(16) __fp16 s[2 * PTOT * 64];   // 40KB
    {   // zero-fill (covers p<10, p>=138 pad rows)
        uint4 z = make_uint4(0, 0, 0, 0);
        uint4* sp = (uint4*)s;
#pragma unroll
        for (int k = 0; k < 10; ++k) sp[k * 256 + tid] = z;
    }
    __syncthreads();
    int w = tid & 127, ch = tid >> 7;
    int p = w + RAD;
#pragma unroll
    for (int t8 = 0; t8 < 8; ++t8) {
        float v[8];
#pragma unroll
        for (int j = 0; j < 8; ++j)
            v[j] = tg[(size_t)(ch * 64 + t8 * 8 + j) * (HH * WW) + w];
        PK q;
        q.h[0] = __builtin_amdgcn_cvt_pkrtz(v[0], v[1]);
        q.h[1] = __builtin_amdgcn_cvt_pkrtz(v[2], v[3]);
        q.h[2] = __builtin_amdgcn_cvt_pkrtz(v[4], v[5]);
        q.h[3] = __builtin_amdgcn_cvt_pkrtz(v[6], v[7]);
        int slot = t8 ^ (p & 7);
        *(uint4*)&s[(ch * PTOT + p) * 64 + slot * 8] = q.u;
    }
    __syncthreads();
    const uint4* si = (const uint4*)s;
#pragma unroll
    for (int k = 0; k < 10; ++k) gi[k * 256 + tid] = si[k * 256 + tid];
}

// ---------------- kernel 2: fused src-pack + pipelined banded MFMA ----------------
__global__ __launch_bounds__(256, 2)
void corr_mfma(const float* __restrict__ in, const __fp16* __restrict__ img_tgt,
               float* __restrict__ out) {
    int n = blockIdx.x;                 // 512
    int xcd = n & 7, idx = n >> 3;
    int gl = xcd * 64 + idx;            // h-contiguous per XCD
    int b = gl >> 7, h = gl & 127;

    __shared__ __align__(16) char smem0[32768];            // s_src, later overlaid by s_o
    __shared__ __align__(16) __fp16 s_tgt[2][PTOT * 64];   // 2 x 20KB double buffer

    __fp16* s_src = (__fp16*)smem0;
    float*  s_o   = (float*)smem0;      // 4 waves x 32 rows x 50 = 25.6KB <= 32KB

    int tid = threadIdx.x;
    int q = tid >> 6, lane = tid & 63, r = lane & 15, g = lane >> 4;

    // ---- pack src slice (b,h): fp32 [c][w] -> f16 [w][c] swizzled, x 1/128 ----
    {
        const float* src = in + (size_t)(b * 2) * CCH * HH * WW + (size_t)h * WW;
        const float sc = 1.f / 128.f;
        int w = tid & 127, half = tid >> 7;
#pragma unroll
        for (int t8 = 0; t8 < 8; ++t8) {
            int t = half * 8 + t8;          // c-block 0..15
            float v[8];
#pragma unroll
            for (int j = 0; j < 8; ++j) v[j] = src[(size_t)(t * 8 + j) * (HH * WW) + w] * sc;
            PK qq;
            qq.h[0] = __builtin_amdgcn_cvt_pkrtz(v[0], v[1]);
            qq.h[1] = __builtin_amdgcn_cvt_pkrtz(v[2], v[3]);
            qq.h[2] = __builtin_amdgcn_cvt_pkrtz(v[4], v[5]);
            qq.h[3] = __builtin_amdgcn_cvt_pkrtz(v[6], v[7]);
            int slot = t ^ (w & 7);
            *(uint4*)&s_src[w * 128 + slot * 8] = qq.u;
        }
    }
    __syncthreads();

    // ---- A-fragments to registers (whole kernel): wave q owns w-tiles 2q,2q+1 ----
    f16x8 a[2][4];
#pragma unroll
    for (int wi = 0; wi < 2; ++wi) {
        int wrow = (2 * q + wi) * 16 + r;
#pragma unroll
        for (int ks = 0; ks < 4; ++ks) {
            int slot = (ks * 4 + g) ^ (wrow & 7);
            a[wi][ks] = *(const f16x8*)&s_src[wrow * 128 + slot * 8];
        }
    }
    asm volatile("s_waitcnt lgkmcnt(0)" ::: "memory");   // a-frags in regs before s_o overlay

    const __fp16* tgb = img_tgt + (size_t)(b * HPAD) * TGT_IMG_HALVES;
    float* outb = out + (size_t)b * (NKD * NKD) * (HH * WW) + (size_t)h * WW;
    float* so = s_o + q * (32 * 50);

    // DMA one 20KB chunk (hp, chv) into s_tgt[bufi]; wave q copies 320 uint4
    auto stage = [&](int hp, int chv, int bufi) {
        const uint4* gsrc = (const uint4*)(tgb + (size_t)hp * TGT_IMG_HALVES)
                            + chv * 1280 + q * 320 + lane;
        char* ldst = (char*)&s_tgt[bufi][0] + q * 5120;
#pragma unroll
        for (int k = 0; k < 5; ++k)
            __builtin_amdgcn_global_load_lds(
                (const __attribute__((address_space(1))) void*)(gsrc + k * 64),
                (__attribute__((address_space(3))) void*)(ldst + k * 1024),
                16, 0, 0);
    };

    stage(h, 0, 0);
    __syncthreads();   // __syncthreads drains vmcnt(0): chunk(dy0,ch0) landed

    for (int dy = 0; dy < NKD; ++dy) {
        f32x4 acc[2][3];
#pragma unroll
        for (int wi = 0; wi < 2; ++wi)
#pragma unroll
            for (int pj = 0; pj < 3; ++pj)
#pragma unroll
                for (int j = 0; j < 4; ++j) acc[wi][pj][j] = 0.f;

        // ===== phase A: prefetch (dy,ch1)->buf1, compute (dy,ch0) from buf0 =====
        stage(h + dy, 1, 1);
#pragma unroll
        for (int ks2 = 0; ks2 < 2; ++ks2) {
            f16x8 bfr[4];
#pragma unroll
            for (int pi = 0; pi < 4; ++pi) {
                int prow = (2 * q + pi) * 16 + r;
                int slot = (ks2 * 4 + g) ^ (prow & 7);
                bfr[pi] = *(const f16x8*)&s_tgt[0][prow * 64 + slot * 8];
            }
#pragma unroll
            for (int wi = 0; wi < 2; ++wi)
#pragma unroll
                for (int pj = 0; pj < 3; ++pj)
                    acc[wi][pj] = __builtin_amdgcn_mfma_f32_16x16x32_f16(
                        a[wi][ks2], bfr[wi + pj], acc[wi][pj], 0, 0, 0);
        }
        __syncthreads();   // drains buf1 DMA; all waves done reading buf0

        // ===== phase B: prefetch (dy+1,ch0)->buf0, compute (dy,ch1) from buf1 =====
        if (dy + 1 < NKD) stage(h + dy + 1, 0, 0);
#pragma unroll
        for (int ks2 = 0; ks2 < 2; ++ks2) {
            f16x8 bfr[4];
#pragma unroll
            for (int pi = 0; pi < 4; ++pi) {
                int prow = (2 * q + pi) * 16 + r;
                int slot = (ks2 * 4 + g) ^ (prow & 7);
                bfr[pi] = *(const f16x8*)&s_tgt[1][prow * 64 + slot * 8];
            }
#pragma unroll
            for (int wi = 0; wi < 2; ++wi)
#pragma unroll
                for (int pj = 0; pj < 3; ++pj)
                    acc[wi][pj] = __builtin_amdgcn_mfma_f32_16x16x32_f16(
                        a[wi][2 + ks2], bfr[wi + pj], acc[wi][pj], 0, 0, 0);
        }

        // ---- wave-local epilogue: acc -> private s_o slab (stride 50), store ----
#pragma unroll
        for (int wi = 0; wi < 2; ++wi)
#pragma unroll
            for (int pj = 0; pj < 3; ++pj)
#pragma unroll
                for (int j = 0; j < 4; ++j)
                    so[(wi * 16 + 4 * g + j) * 50 + pj * 16 + r] = acc[wi][pj][j];
        asm volatile("s_waitcnt lgkmcnt(0)" ::: "memory");
        __builtin_amdgcn_sched_barrier(0);
#pragma unroll
        for (int k = 0; k < 3; ++k) {
            int f = k * 64 + lane;
            if (f < NKD * 8) {
                int dx = f >> 3, w4l = (f & 7) << 2;   // local w in wave's 32-w slab
                float4 v;
                v.x = so[(w4l + 0) * 50 + ((w4l + 0) & 15) + dx];
                v.y = so[(w4l + 1) * 50 + ((w4l + 1) & 15) + dx];
                v.z = so[(w4l + 2) * 50 + ((w4l + 2) & 15) + dx];
                v.w = so[(w4l + 3) * 50 + ((w4l + 3) & 15) + dx];
                *(float4*)&outb[(size_t)(dy * NKD + dx) * (HH * WW) + q * 32 + w4l] = v;
            }
        }
        __syncthreads();   // drains buf0 DMA; all waves done reading buf1 & s_o safe
    }
}

extern "C" void kernel_launch(void* const* d_in, const int* in_sizes, int n_in,
                              void* d_out, int out_size, void* d_ws, size_t ws_size,
                              hipStream_t stream) {
    const float* in = (const float*)d_in[0];
    float* out = (float*)d_out;
    __fp16* img_tgt = (__fp16*)d_ws;

    hipLaunchKernelGGL(pack_tgt, dim3(4 * HPAD), dim3(256), 0, stream, in, img_tgt);
    hipLaunchKernelGGL(corr_mfma, dim3(512), dim3(256), 0, stream, in, img_tgt, out);
}

// Round 7
// 59.757 us; speedup vs baseline: 5.8963x; 1.0344x over previous
//
#include <hip/hip_runtime.h>

#define HH 128
#define WW 128
#define CCH 128
#define NKD 21
#define RAD 10
#define HPAD 148                 // tgt images per b (hp = h+dy, 0..147)
#define ROWH 40                  // halves per row (32c + 8 pad) = 80B
#define CH_HALVES (148 * ROWH)   // 5920 halves per chunk (148 p-rows)
#define CH_BYTES  (CH_HALVES * 2)        // 11840 B
#define IMG_HALVES (4 * CH_HALVES)       // 23680 halves per (b,hp) = 47360 B

typedef _Float16 f16x8 __attribute__((ext_vector_type(8)));
typedef float    f32x4 __attribute__((ext_vector_type(4)));
typedef __fp16   h2f   __attribute__((ext_vector_type(2)));

union PK { uint4 u; h2f h[4]; };

// ------- kernel 1: pack tgt -> f16 image [hp][chunk(32c)][p(148)][40 halves], zero-padded -------
__global__ __launch_bounds__(256)
void pack_tgt(const float* __restrict__ in, __fp16* __restrict__ img) {
    int n = blockIdx.x;                 // 592: b*148 + i (tgt row = i-10)
    int b = n / HPAD, i = n - b * HPAD;
    int tid = threadIdx.x;
    uint4* gi = (uint4*)(img + (size_t)n * IMG_HALVES);
    if (i < RAD || i > 137) {           // h out of range -> all-zero image (2960 uint4)
        uint4 z = make_uint4(0, 0, 0, 0);
#pragma unroll
        for (int k = 0; k < 11; ++k) gi[k * 256 + tid] = z;
        if (tid < 144) gi[11 * 256 + tid] = z;
        return;
    }
    __shared__ __align__(16) char sraw[4 * CH_BYTES];   // 46.25KB
    {   // zero-fill (covers p<10, p>137 pad rows and the 8-half row tail)
        uint4 z = make_uint4(0, 0, 0, 0);
        uint4* sp = (uint4*)sraw;
#pragma unroll
        for (int k = 0; k < 11; ++k) sp[k * 256 + tid] = z;
        if (tid < 144) sp[11 * 256 + tid] = z;
    }
    __syncthreads();
    const float* tg = in + (size_t)(b * 2 + 1) * CCH * HH * WW + (size_t)(i - RAD) * WW;
    int w = tid & 127, half = tid >> 7;
    int p = w + RAD;                    // 10..137
#pragma unroll
    for (int c2 = 0; c2 < 2; ++c2) {
        int cc = half * 2 + c2;         // chunk 0..3 (32 channels each)
#pragma unroll
        for (int g = 0; g < 4; ++g) {   // slot g = halves c_local g*8..g*8+7
            float v[8];
#pragma unroll
            for (int j = 0; j < 8; ++j)
                v[j] = tg[(size_t)(cc * 32 + g * 8 + j) * (HH * WW) + w];
            PK q;
            q.h[0] = __builtin_amdgcn_cvt_pkrtz(v[0], v[1]);
            q.h[1] = __builtin_amdgcn_cvt_pkrtz(v[2], v[3]);
            q.h[2] = __builtin_amdgcn_cvt_pkrtz(v[4], v[5]);
            q.h[3] = __builtin_amdgcn_cvt_pkrtz(v[6], v[7]);
            *(uint4*)(sraw + (size_t)cc * CH_BYTES + p * 80 + g * 16) = q.u;
        }
    }
    __syncthreads();
    const uint4* si = (const uint4*)sraw;
#pragma unroll
    for (int k = 0; k < 11; ++k) gi[k * 256 + tid] = si[k * 256 + tid];
    if (tid < 144) gi[11 * 256 + tid] = si[11 * 256 + tid];
}

// ---------------- kernel 2: fused src-pack + ring-pipelined banded MFMA ----------------
__global__ __launch_bounds__(256, 2)
void corr_mfma(const float* __restrict__ in, const __fp16* __restrict__ img_tgt,
               float* __restrict__ out) {
    int n = blockIdx.x;                 // 512
    int xcd = n & 7, idx = n >> 3;
    int gl = xcd * 64 + idx;            // h-contiguous per XCD
    int b = gl >> 7, h = gl & 127;

    // [ring 4 x 11840B][overlay 32KB: s_src then s_o] = 80128B -> 2 blocks/CU
    __shared__ __align__(16) char smem[4 * CH_BYTES + 32768];
    char*   s_ring = smem;
    __fp16* s_src  = (__fp16*)(smem + 4 * CH_BYTES);
    float*  s_o    = (float*)(smem + 4 * CH_BYTES);

    int tid = threadIdx.x;
    int q = tid >> 6, lane = tid & 63, r = lane & 15, g = lane >> 4;

    const __fp16* tgb = img_tgt + (size_t)(b * HPAD) * IMG_HALVES;

    // DMA one chunk t=(dy*4+cc) into ring slot t&3; wave q copies 185 uint4 (2 full + lane<57)
    auto stage = [&](int t) {
        int dyp = t >> 2, ccp = t & 3;
        const uint4* gp = (const uint4*)(tgb + ((size_t)(h + dyp) * 4 + ccp) * CH_HALVES)
                          + q * 185 + lane;
        char* lb = s_ring + (size_t)(t & 3) * CH_BYTES + q * 2960;
        __builtin_amdgcn_global_load_lds(
            (const __attribute__((address_space(1))) void*)gp,
            (__attribute__((address_space(3))) void*)lb, 16, 0, 0);
        __builtin_amdgcn_global_load_lds(
            (const __attribute__((address_space(1))) void*)(gp + 64),
            (__attribute__((address_space(3))) void*)(lb + 1024), 16, 0, 0);
        if (lane < 57)
            __builtin_amdgcn_global_load_lds(
                (const __attribute__((address_space(1))) void*)(gp + 128),
                (__attribute__((address_space(3))) void*)(lb + 2048), 16, 0, 0);
    };

    // prefetch chunks 0,1 while we pack src
    stage(0);
    stage(1);

    // ---- pack src slice (b,h): fp32 [c][w] -> f16 [w][c] swizzled, x 1/128 ----
    {
        const float* src = in + (size_t)(b * 2) * CCH * HH * WW + (size_t)h * WW;
        const float sc = 1.f / 128.f;
        int w = tid & 127, half = tid >> 7;
#pragma unroll
        for (int t8 = 0; t8 < 8; ++t8) {
            int t = half * 8 + t8;          // c-block 0..15
            float v[8];
#pragma unroll
            for (int j = 0; j < 8; ++j) v[j] = src[(size_t)(t * 8 + j) * (HH * WW) + w] * sc;
            PK qq;
            qq.h[0] = __builtin_amdgcn_cvt_pkrtz(v[0], v[1]);
            qq.h[1] = __builtin_amdgcn_cvt_pkrtz(v[2], v[3]);
            qq.h[2] = __builtin_amdgcn_cvt_pkrtz(v[4], v[5]);
            qq.h[3] = __builtin_amdgcn_cvt_pkrtz(v[6], v[7]);
            int slot = t ^ (w & 7);
            *(uint4*)&s_src[w * 128 + slot * 8] = qq.u;
        }
    }
    __syncthreads();   // drains vmcnt too: chunks 0,1 landed; count logic below stays sound

    // ---- A-fragments to registers (whole kernel): wave q owns w-tiles 2q,2q+1 ----
    f16x8 a[2][4];
#pragma unroll
    for (int wi = 0; wi < 2; ++wi) {
        int wrow = (2 * q + wi) * 16 + r;
#pragma unroll
        for (int ks = 0; ks < 4; ++ks) {
            int slot = (ks * 4 + g) ^ (wrow & 7);
            a[wi][ks] = *(const f16x8*)&s_src[wrow * 128 + slot * 8];
        }
    }
    asm volatile("s_waitcnt lgkmcnt(0)" ::: "memory");   // a-frags in regs before s_o overlay

    float* outb = out + (size_t)b * (NKD * NKD) * (HH * WW) + (size_t)h * WW;
    float* so = s_o + q * (32 * 50);

    // Main loop: 84 phases (21 dy x 4 chunk-phases), ring prefetch depth 2.
    // vmcnt FIFO per wave (3 loads/stage, 3 stores/epilogue, in-order retire):
    //   cc0: [t,t+1,S,t+2] -> vmcnt(9) retires t.  cc1: [t,S,t+1,t+2] -> vmcnt(9).
    //   cc2: [S,t,t+1,t+2] -> vmcnt(6) retires S,t.  cc3: [t,t+1,t+2] -> vmcnt(6).
    //   dy==20 tails: cc2 -> vmcnt(3), cc3 -> vmcnt(0).
    // Slot overwritten at phase t+... is the slot of chunk t-2: its readers passed
    // >=1 barrier before the stage issues -> race-free.
    for (int dy = 0; dy < NKD; ++dy) {
        f32x4 acc[2][3];
#pragma unroll
        for (int wi = 0; wi < 2; ++wi)
#pragma unroll
            for (int pj = 0; pj < 3; ++pj)
#pragma unroll
                for (int j = 0; j < 4; ++j) acc[wi][pj][j] = 0.f;

#pragma unroll
        for (int cc = 0; cc < 4; ++cc) {
            int t = dy * 4 + cc;
            if (cc < 2)            stage(t + 2);
            else if (dy < NKD - 1) stage(t + 2);

            if (cc < 2) {
                asm volatile("s_waitcnt vmcnt(9)" ::: "memory");
            } else if (dy < NKD - 1) {
                asm volatile("s_waitcnt vmcnt(6)" ::: "memory");
            } else if (cc == 2) {
                asm volatile("s_waitcnt vmcnt(3)" ::: "memory");
            } else {
                asm volatile("s_waitcnt vmcnt(0)" ::: "memory");
            }
            __builtin_amdgcn_s_barrier();
            __builtin_amdgcn_sched_barrier(0);

            const char* buf = s_ring + (size_t)(t & 3) * CH_BYTES;
            f16x8 bfr[4];
#pragma unroll
            for (int pi = 0; pi < 4; ++pi) {
                int prow = (2 * q + pi) * 16 + r;   // reads past p=147 feed discarded cols
                bfr[pi] = *(const f16x8*)(buf + prow * 80 + g * 16);
            }
#pragma unroll
            for (int wi = 0; wi < 2; ++wi)
#pragma unroll
                for (int pj = 0; pj < 3; ++pj)
                    acc[wi][pj] = __builtin_amdgcn_mfma_f32_16x16x32_f16(
                        a[wi][cc], bfr[wi + pj], acc[wi][pj], 0, 0, 0);
        }

        // ---- wave-local epilogue: acc -> private s_o slab (stride 50), coalesced stores ----
#pragma unroll
        for (int wi = 0; wi < 2; ++wi)
#pragma unroll
            for (int pj = 0; pj < 3; ++pj)
#pragma unroll
                for (int j = 0; j < 4; ++j)
                    so[(wi * 16 + 4 * g + j) * 50 + pj * 16 + r] = acc[wi][pj][j];
        asm volatile("s_waitcnt lgkmcnt(0)" ::: "memory");
        __builtin_amdgcn_sched_barrier(0);
#pragma unroll
        for (int k = 0; k < 3; ++k) {     // exactly 3 store instrs per wave (vmcnt model)
            int f = k * 64 + lane;
            if (f < NKD * 8) {
                int dx = f >> 3, w4l = (f & 7) << 2;   // local w in wave's 32-w slab
                float4 v;
                v.x = so[(w4l + 0) * 50 + ((w4l + 0) & 15) + dx];
                v.y = so[(w4l + 1) * 50 + ((w4l + 1) & 15) + dx];
                v.z = so[(w4l + 2) * 50 + ((w4l + 2) & 15) + dx];
                v.w = so[(w4l + 3) * 50 + ((w4l + 3) & 15) + dx];
                *(float4*)&outb[(size_t)(dy * NKD + dx) * (HH * WW) + q * 32 + w4l] = v;
            }
        }
    }
}

extern "C" void kernel_launch(void* const* d_in, const int* in_sizes, int n_in,
                              void* d_out, int out_size, void* d_ws, size_t ws_size,
                              hipStream_t stream) {
    const float* in = (const float*)d_in[0];
    float* out = (float*)d_out;
    __fp16* img_tgt = (__fp16*)d_ws;

    hipLaunchKernelGGL(pack_tgt, dim3(4 * HPAD), dim3(256), 0, stream, in, img_tgt);
    hipLaunchKernelGGL(corr_mfma, dim3(512), dim3(256), 0, stream, in, img_tgt, out);
}